// Round 8
// baseline (322.505 us; speedup 1.0000x reference)
//
#include <hip/hip_runtime.h>
#include <hip/hip_bf16.h>

typedef __bf16 bf16x8 __attribute__((ext_vector_type(8)));
typedef __bf16 bf16x4 __attribute__((ext_vector_type(4)));
typedef float  f32x4  __attribute__((ext_vector_type(4)));
typedef float  f32x16 __attribute__((ext_vector_type(16)));

// ---------------------------------------------------------------------------
// Kernel 1: prep (unchanged — validated)
// ---------------------------------------------------------------------------
__global__ __launch_bounds__(256) void prep_kernel(
    const float* __restrict__ img, const float* __restrict__ ques,
    const float* __restrict__ g_w1, const float* __restrict__ g_b1,
    const float* __restrict__ g_w2, const float* __restrict__ g_w3,
    const float* __restrict__ g_w4,
    float* __restrict__ U, float* __restrict__ V, float* __restrict__ Qb,
    __bf16* __restrict__ W2t, __bf16* __restrict__ W3t, __bf16* __restrict__ W4t) {
  __shared__ float smem[64 * 65];
  const int blk = blockIdx.x;
  const int t = threadIdx.x;

  if (blk < 256) {
    const int n = blk >> 2, obase = (blk & 3) * 16;
    for (int idx = t; idx < 66 * 16; idx += 256) {
      const int c = idx >> 4, o = obase + (idx & 15);
      float v;
      if (c < 64)      v = img[n * 4096 + c * 64 + o];
      else if (c == 64) v = (float)(o >> 3);
      else              v = (float)(o & 7);
      smem[idx] = v;
    }
    __syncthreads();
    float u[16], vv[16];
#pragma unroll
    for (int o = 0; o < 16; ++o) { u[o] = 0.f; vv[o] = 0.f; }
    for (int d = 0; d < 66; ++d) {
      const float wu = g_w1[d * 256 + t];
      const float wv = g_w1[(66 + d) * 256 + t];
#pragma unroll
      for (int o = 0; o < 16; ++o) {
        const float cc = smem[d * 16 + o];
        u[o]  += cc * wu;
        vv[o] += cc * wv;
      }
    }
#pragma unroll
    for (int o = 0; o < 16; ++o) {
      U[(size_t)(n * 64 + obase + o) * 256 + t] = u[o];
      V[(size_t)(n * 64 + obase + o) * 256 + t] = vv[o];
    }
  } else if (blk < 320) {
    const int n = blk - 256;
    smem[t] = ques[n * 256 + t];
    __syncthreads();
    float s = g_b1[t];
    for (int e = 0; e < 256; ++e) s += smem[e] * g_w1[(132 + e) * 256 + t];
    Qb[n * 256 + t] = s;
  } else {
    const int b2 = blk - 320;
    const int wsel = b2 >> 4;
    const int tile = b2 & 15;
    const int r0 = (tile >> 2) * 64, c0 = (tile & 3) * 64;
    const float* W = (wsel == 0) ? g_w2 : (wsel == 1) ? g_w3 : g_w4;
    __bf16* Wt    = (wsel == 0) ? W2t  : (wsel == 1) ? W3t  : W4t;
    const int col = t & 63, rb = (t >> 6) * 16;
#pragma unroll 4
    for (int j = 0; j < 16; ++j)
      smem[(rb + j) * 65 + col] = W[(size_t)(r0 + rb + j) * 256 + c0 + col];
    __syncthreads();
#pragma unroll 4
    for (int j = 0; j < 16; ++j)
      Wt[(size_t)(c0 + rb + j) * 256 + r0 + col] = (__bf16)smem[col * 65 + rb + j];
  }
}

// ---------------------------------------------------------------------------
// Kernel 2: fused g-MLP layers 2..4. 256 thr / 4 waves, one (n,i) per block.
//  32x32x16 MFMA: wave = 64 rows x 64-col strip = 2(mt) x 2(nt) tiles,
//  acc = 4 x f32x16 (64 AGPR). 16 K-steps, 4 MFMA + 2 ds_read + 2 global/step.
//  Operands: mfma(W_frag, H_frag, acc):
//    H (B-pos): lane reads H[row = mt*32 + (lane&31)][k = ksb*16 + q*8 .. +7]
//    W (A-pos): lane reads Wt[(strip*64 + nt*32 + (lane&31))*256 + ksb*16 + q*8]
//    C/D: H-row(n) = lane&31, W-col(m) = (reg&3) + 8*(reg>>2) + 4*q
//  Explicit 2-deep double-buffer for BOTH H (LDS) and W (global), W ring rolls
//  across layer boundaries. Regs: 64 AGPR + ~70 VGPR < 170 cap -> no spill.
//  Slab elem(row,c) = (c>>3)*512 + ((row+(c>>3))&63)*8 + (c&7)
// ---------------------------------------------------------------------------
#define HSZ 16384   // bf16 elems (32 KB)

__device__ __forceinline__ int hidx(int row, int c) {
  const int kb = c >> 3;
  return kb * 512 + (((row + kb) & 63) << 3) + (c & 7);
}

#define MFMA32(A, B, C) __builtin_amdgcn_mfma_f32_32x32x16_bf16(A, B, C, 0, 0, 0)

template <bool LAST>
__device__ __forceinline__ void g_layer32(__bf16* Hs, bf16x8 wring[2][2],
                                          const __bf16* __restrict__ w0,
                                          const __bf16* __restrict__ w1,
                                          const __bf16* __restrict__ wn0,
                                          const __bf16* __restrict__ wn1,
                                          const float* __restrict__ bias_g,
                                          int strip, int l31, int q,
                                          float* __restrict__ part_row) {
  f32x16 acc[2][2];
#pragma unroll
  for (int mt = 0; mt < 2; ++mt)
#pragma unroll
    for (int nt = 0; nt < 2; ++nt)
#pragma unroll
      for (int e = 0; e < 16; ++e) acc[mt][nt][e] = 0.f;

  // prologue: H fragments for ksb = 0 (wring[0] was pre-filled by caller /
  // previous layer's cross-layer prefetch)
  bf16x8 hb[2][2];
  {
    const int kb = q;  // ksb=0
    hb[0][0] = *(const bf16x8*)(&Hs[kb * 512 + (((l31 + kb) & 63) << 3)]);
    hb[0][1] = *(const bf16x8*)(&Hs[kb * 512 + (((32 + l31 + kb) & 63) << 3)]);
  }

#pragma unroll
  for (int ksb = 0; ksb < 16; ++ksb) {
    const int cur = ksb & 1, nxt = cur ^ 1;
    if (ksb < 15) {
      wring[nxt][0] = *(const bf16x8*)(w0 + (ksb + 1) * 16);
      wring[nxt][1] = *(const bf16x8*)(w1 + (ksb + 1) * 16);
      const int kb = (ksb + 1) * 2 + q;
      hb[nxt][0] = *(const bf16x8*)(&Hs[kb * 512 + (((l31 + kb) & 63) << 3)]);
      hb[nxt][1] = *(const bf16x8*)(&Hs[kb * 512 + (((32 + l31 + kb) & 63) << 3)]);
    } else if (!LAST) {
      // cross-layer prefetch: next layer's ksb = 0
      wring[nxt][0] = *(const bf16x8*)(wn0);
      wring[nxt][1] = *(const bf16x8*)(wn1);
    }
    acc[0][0] = MFMA32(wring[cur][0], hb[cur][0], acc[0][0]);
    acc[0][1] = MFMA32(wring[cur][1], hb[cur][0], acc[0][1]);
    acc[1][0] = MFMA32(wring[cur][0], hb[cur][1], acc[1][0]);
    acc[1][1] = MFMA32(wring[cur][1], hb[cur][1], acc[1][1]);
  }

  if (!LAST) {
    __syncthreads();   // all waves done reading Hs
#pragma unroll
    for (int nt = 0; nt < 2; ++nt)
#pragma unroll
      for (int g = 0; g < 4; ++g) {
        const int cb = strip * 64 + nt * 32 + g * 8 + q * 4;
        const f32x4 bv = *(const f32x4*)&bias_g[cb];
#pragma unroll
        for (int mt = 0; mt < 2; ++mt) {
          bf16x4 h;
#pragma unroll
          for (int e = 0; e < 4; ++e)
            h[e] = (__bf16)fmaxf(acc[mt][nt][g * 4 + e] + bv[e], 0.f);
          *(bf16x4*)(&Hs[hidx(mt * 32 + l31, cb)]) = h;
        }
      }
    __syncthreads();
  } else {
    // sum relu over 64 rows: in-thread over mt, shuffle over lane&31
#pragma unroll
    for (int nt = 0; nt < 2; ++nt)
#pragma unroll
      for (int g = 0; g < 4; ++g) {
        const int cb = strip * 64 + nt * 32 + g * 8 + q * 4;
        const f32x4 bv = *(const f32x4*)&bias_g[cb];
        f32x4 s;
#pragma unroll
        for (int e = 0; e < 4; ++e)
          s[e] = fmaxf(acc[0][nt][g * 4 + e] + bv[e], 0.f)
               + fmaxf(acc[1][nt][g * 4 + e] + bv[e], 0.f);
#pragma unroll
        for (int d = 1; d < 32; d <<= 1) {
#pragma unroll
          for (int e = 0; e < 4; ++e) s[e] += __shfl_xor(s[e], d, 64);
        }
        if (l31 == 0) *(f32x4*)&part_row[cb] = s;   // lanes 0 (q=0) and 32 (q=1)
      }
  }
}

__global__ __launch_bounds__(256, 3) void rn_main(
    const float* __restrict__ U, const float* __restrict__ V,
    const float* __restrict__ Qb,
    const __bf16* __restrict__ Wt,   // W2t; W3t = +65536, W4t = +131072 elems
    const float* __restrict__ b2, const float* __restrict__ b3,
    const float* __restrict__ b4,
    float* __restrict__ part) {
  __shared__ __align__(16) __bf16 Hs[HSZ];   // 32 KB
  // XCD-aware swizzle: block b -> XCD (b&7); give each XCD 8 whole images
  // so V[n] becomes L2-local. Mapping is a perf heuristic only.
  const int b = blockIdx.x;
  const int loc = b >> 3;
  const int nimg = (b & 7) * 8 + (loc >> 6);
  const int iobj = loc & 63;
  const int t = threadIdx.x;
  const int strip = t >> 6, lane = t & 63;
  const int l31 = lane & 31, q = lane >> 5;

  // lane-resolved W base: channel = strip*64 + nt*32 + l31, K offset q*8
  const __bf16* w0 = Wt + (size_t)(strip * 64 + l31) * 256 + q * 8;
  const __bf16* w1 = w0 + 8192;    // nt=1 (+32 channels)

  // fill W ring slot 0 for layer 2, ksb=0 (issues before phase-0 math)
  bf16x8 wring[2][2];
  wring[0][0] = *(const bf16x8*)w0;
  wring[0][1] = *(const bf16x8*)w1;

  // phase 0: h1[j][:] = relu(U[n,i,:] + V[n,j,:] + Qb[n,:]) -> Hs
  {
    const int c4 = t & 63;          // col-quad: cols 4*c4..4*c4+3
    const int jb = (t >> 6) * 16;   // 16 rows per thread
    const f32x4 u4 = *(const f32x4*)&U[(size_t)(nimg * 64 + iobj) * 256 + c4 * 4];
    const f32x4 q4 = *(const f32x4*)&Qb[(size_t)nimg * 256 + c4 * 4];
    const f32x4 uq = u4 + q4;
#pragma unroll
    for (int jj = 0; jj < 16; ++jj) {
      const int row = jb + jj;
      const f32x4 v4 = *(const f32x4*)&V[(size_t)(nimg * 64 + row) * 256 + c4 * 4];
      bf16x4 h;
#pragma unroll
      for (int r = 0; r < 4; ++r) h[r] = (__bf16)fmaxf(uq[r] + v4[r], 0.f);
      *(bf16x4*)(&Hs[hidx(row, c4 * 4)]) = h;
    }
  }
  __syncthreads();

  float* part_row = part + (size_t)(nimg * 64 + iobj) * 256;

  g_layer32<false>(Hs, wring, w0,          w1,          w0 +  65536, w1 +  65536,
                   b2, strip, l31, q, part_row);
  g_layer32<false>(Hs, wring, w0 +  65536, w1 +  65536, w0 + 131072, w1 + 131072,
                   b3, strip, l31, q, part_row);
  g_layer32<true >(Hs, wring, w0 + 131072, w1 + 131072, w0,          w1,
                   b4, strip, l31, q, part_row);
}

// ---------------------------------------------------------------------------
// Kernel 3: reduce partials -> context, f-MLP (fp32), log_softmax
// ---------------------------------------------------------------------------
__global__ __launch_bounds__(256) void rn_final(
    const float* __restrict__ part,
    const float* __restrict__ f_w1, const float* __restrict__ f_b1,
    const float* __restrict__ f_w2, const float* __restrict__ f_b2,
    const float* __restrict__ f_w3, const float* __restrict__ f_b3,
    float* __restrict__ out) {
  __shared__ float ctx[256], y1[256], y2[256], sc[2];
  const int n = blockIdx.x, t = threadIdx.x;

  float s = 0.f;
  for (int i = 0; i < 64; ++i) s += part[((size_t)n * 64 + i) * 256 + t];
  ctx[t] = s * (1.0f / 4096.0f);
  __syncthreads();

  float a = f_b1[t];
  for (int k = 0; k < 256; ++k) a += ctx[k] * f_w1[k * 256 + t];
  y1[t] = fmaxf(a, 0.f);
  __syncthreads();

  float b = f_b2[t];
  for (int k = 0; k < 256; ++k) b += y1[k] * f_w2[k * 256 + t];
  y2[t] = fmaxf(b, 0.f);
  __syncthreads();

  if (t < 2) {
    float c = f_b3[t];
    for (int k = 0; k < 256; ++k) c += y2[k] * f_w3[k * 2 + t];
    sc[t] = c;
  }
  __syncthreads();

  if (t == 0) {
    const float s0 = sc[0], s1 = sc[1];
    const float mx = fmaxf(s0, s1);
    const float lse = mx + logf(expf(s0 - mx) + expf(s1 - mx));
    out[n * 2 + 0] = s0 - lse;
    out[n * 2 + 1] = s1 - lse;
  }
}

// ---------------------------------------------------------------------------
extern "C" void kernel_launch(void* const* d_in, const int* in_sizes, int n_in,
                              void* d_out, int out_size, void* d_ws, size_t ws_size,
                              hipStream_t stream) {
  const float* img  = (const float*)d_in[0];
  const float* ques = (const float*)d_in[1];
  const float* g_w1 = (const float*)d_in[2];
  const float* g_b1 = (const float*)d_in[3];
  const float* g_w2 = (const float*)d_in[4];
  const float* g_b2 = (const float*)d_in[5];
  const float* g_w3 = (const float*)d_in[6];
  const float* g_b3 = (const float*)d_in[7];
  const float* g_w4 = (const float*)d_in[8];
  const float* g_b4 = (const float*)d_in[9];
  const float* f_w1 = (const float*)d_in[10];
  const float* f_b1 = (const float*)d_in[11];
  const float* f_w2 = (const float*)d_in[12];
  const float* f_b2 = (const float*)d_in[13];
  const float* f_w3 = (const float*)d_in[14];
  const float* f_b3 = (const float*)d_in[15];
  float* out = (float*)d_out;

  char* ws = (char*)d_ws;
  float*  U    = (float*)(ws);                                 // 4 MB
  float*  V    = (float*)(ws + (size_t)4  * 1048576);          // 4 MB
  float*  part = (float*)(ws + (size_t)8  * 1048576);          // 4 MB
  float*  Qb   = (float*)(ws + (size_t)12 * 1048576);          // 64 KB
  __bf16* W2t  = (__bf16*)(ws + (size_t)12 * 1048576 + 65536); // contiguous
  __bf16* W3t  = W2t + 65536;
  __bf16* W4t  = W3t + 65536;

  prep_kernel<<<368, 256, 0, stream>>>(img, ques, g_w1, g_b1, g_w2, g_w3, g_w4,
                                       U, V, Qb, W2t, W3t, W4t);
  rn_main<<<4096, 256, 0, stream>>>(U, V, Qb, W2t, g_b2, g_b3, g_b4, part);
  rn_final<<<64, 256, 0, stream>>>(part, f_w1, f_b1, f_w2, f_b2, f_w3, f_b3, out);
}

// Round 9
// 310.086 us; speedup vs baseline: 1.0401x; 1.0401x over previous
//
#include <hip/hip_runtime.h>
#include <hip/hip_bf16.h>

typedef __bf16 bf16x8 __attribute__((ext_vector_type(8)));
typedef __bf16 bf16x4 __attribute__((ext_vector_type(4)));
typedef float  f32x4  __attribute__((ext_vector_type(4)));

#define WCOPY 196608   // elems per weight-copy (3 layers x 65536)

// ---------------------------------------------------------------------------
// Kernel 1: prep. Same as validated version, but the W transpose branch writes
// 8 replicated copies (de-correlates L2 line contention in rn_main).
// ---------------------------------------------------------------------------
__global__ __launch_bounds__(256) void prep_kernel(
    const float* __restrict__ img, const float* __restrict__ ques,
    const float* __restrict__ g_w1, const float* __restrict__ g_b1,
    const float* __restrict__ g_w2, const float* __restrict__ g_w3,
    const float* __restrict__ g_w4,
    float* __restrict__ U, float* __restrict__ V, float* __restrict__ Qb,
    __bf16* __restrict__ Wrep) {
  __shared__ float smem[64 * 65];
  const int blk = blockIdx.x;
  const int t = threadIdx.x;

  if (blk < 256) {
    const int n = blk >> 2, obase = (blk & 3) * 16;
    for (int idx = t; idx < 66 * 16; idx += 256) {
      const int c = idx >> 4, o = obase + (idx & 15);
      float v;
      if (c < 64)      v = img[n * 4096 + c * 64 + o];
      else if (c == 64) v = (float)(o >> 3);
      else              v = (float)(o & 7);
      smem[idx] = v;
    }
    __syncthreads();
    float u[16], vv[16];
#pragma unroll
    for (int o = 0; o < 16; ++o) { u[o] = 0.f; vv[o] = 0.f; }
    for (int d = 0; d < 66; ++d) {
      const float wu = g_w1[d * 256 + t];
      const float wv = g_w1[(66 + d) * 256 + t];
#pragma unroll
      for (int o = 0; o < 16; ++o) {
        const float cc = smem[d * 16 + o];
        u[o]  += cc * wu;
        vv[o] += cc * wv;
      }
    }
#pragma unroll
    for (int o = 0; o < 16; ++o) {
      U[(size_t)(n * 64 + obase + o) * 256 + t] = u[o];
      V[(size_t)(n * 64 + obase + o) * 256 + t] = vv[o];
    }
  } else if (blk < 320) {
    const int n = blk - 256;
    smem[t] = ques[n * 256 + t];
    __syncthreads();
    float s = g_b1[t];
    for (int e = 0; e < 256; ++e) s += smem[e] * g_w1[(132 + e) * 256 + t];
    Qb[n * 256 + t] = s;
  } else {
    const int b2 = blk - 320;
    const int wsel = b2 >> 4;
    const int tile = b2 & 15;
    const int r0 = (tile >> 2) * 64, c0 = (tile & 3) * 64;
    const float* W = (wsel == 0) ? g_w2 : (wsel == 1) ? g_w3 : g_w4;
    const int col = t & 63, rb = (t >> 6) * 16;
#pragma unroll 4
    for (int j = 0; j < 16; ++j)
      smem[(rb + j) * 65 + col] = W[(size_t)(r0 + rb + j) * 256 + c0 + col];
    __syncthreads();
#pragma unroll 4
    for (int j = 0; j < 16; ++j) {
      const __bf16 v = (__bf16)smem[col * 65 + rb + j];
      const size_t off = (size_t)wsel * 65536 + (size_t)(c0 + rb + j) * 256 + r0 + col;
#pragma unroll
      for (int cp = 0; cp < 8; ++cp)
        Wrep[(size_t)cp * WCOPY + off] = v;
    }
  }
}

// ---------------------------------------------------------------------------
// Kernel 2: fused g-MLP layers 2..4. 256 thr / 4 waves, one (n,i) per block.
//  R7 datapath (proven no-spill): wave = 64 rows x 64-col strip, acc 4x4 f32x4.
//  Anti-hotspot measures (theory: lock-step L2 line contention is the ~3000
//  cyc/K-step stall seen in R1..R8):
//   - weight copy selected by blk&7 (8 replicas)
//   - K-loop rotated by (blk>>3)&7
//   - phase-0 V row sweep rotated by iobj
//  Slab elem(row,c) = (c>>3)*512 + ((row+(c>>3))&63)*8 + (c&7)
// ---------------------------------------------------------------------------
#define HSZ 16384   // bf16 elems (32 KB)

__device__ __forceinline__ int hidx(int row, int c) {
  const int kb = c >> 3;
  return kb * 512 + (((row + kb) & 63) << 3) + (c & 7);
}

template <bool LAST>
__device__ __forceinline__ void g_layer(__bf16* Hs,
                                        const __bf16* __restrict__ wbase,
                                        const float* __restrict__ bias_g,
                                        int ws, int q, int r16, int rot,
                                        float* __restrict__ part_row) {
  f32x4 acc[4][4];
  const f32x4 z = {0.f, 0.f, 0.f, 0.f};
#pragma unroll
  for (int m = 0; m < 4; ++m)
#pragma unroll
    for (int nt = 0; nt < 4; ++nt) acc[m][nt] = z;

#pragma unroll
  for (int ks = 0; ks < 8; ++ks) {
    const int ksr = (ks + rot) & 7;          // rotated K-step
    bf16x8 b[4];
#pragma unroll
    for (int nt = 0; nt < 4; ++nt)
      b[nt] = *(const bf16x8*)(wbase + nt * 4096 + ksr * 32);
    const int kb = ksr * 4 + q;
    bf16x8 a[4];
#pragma unroll
    for (int m = 0; m < 4; ++m) {
      const int row = m * 16 + r16;
      a[m] = *(const bf16x8*)(&Hs[kb * 512 + (((row + kb) & 63) << 3)]);
    }
#pragma unroll
    for (int m = 0; m < 4; ++m)
#pragma unroll
      for (int nt = 0; nt < 4; ++nt)
        // swapped operands (validated): acc[m][nt] -> row m*16+r16,
        // cols ws*64 + nt*16 + q*4 + reg
        acc[m][nt] = __builtin_amdgcn_mfma_f32_16x16x32_bf16(b[nt], a[m], acc[m][nt], 0, 0, 0);
  }

  f32x4 bv[4];
#pragma unroll
  for (int nt = 0; nt < 4; ++nt)
    bv[nt] = *(const f32x4*)&bias_g[ws * 64 + nt * 16 + q * 4];

  if (!LAST) {
    __syncthreads();   // all waves done reading slab
#pragma unroll
    for (int m = 0; m < 4; ++m)
#pragma unroll
      for (int nt = 0; nt < 4; ++nt) {
        const int cb = ws * 64 + nt * 16 + q * 4;
        const f32x4 s = acc[m][nt] + bv[nt];
        bf16x4 h;
#pragma unroll
        for (int r = 0; r < 4; ++r) h[r] = (__bf16)fmaxf(s[r], 0.f);
        *(bf16x4*)(&Hs[hidx(m * 16 + r16, cb)]) = h;
      }
    __syncthreads();
  } else {
#pragma unroll
    for (int nt = 0; nt < 4; ++nt) {
      const int cb = ws * 64 + nt * 16 + q * 4;
      f32x4 s;
#pragma unroll
      for (int r = 0; r < 4; ++r)
        s[r] = fmaxf(acc[0][nt][r] + bv[nt][r], 0.f)
             + fmaxf(acc[1][nt][r] + bv[nt][r], 0.f)
             + fmaxf(acc[2][nt][r] + bv[nt][r], 0.f)
             + fmaxf(acc[3][nt][r] + bv[nt][r], 0.f);
#pragma unroll
      for (int d = 1; d < 16; d <<= 1) {
#pragma unroll
        for (int r = 0; r < 4; ++r) s[r] += __shfl_xor(s[r], d, 64);
      }
      if (r16 == 0) *(f32x4*)&part_row[cb] = s;
    }
  }
}

__global__ __launch_bounds__(256, 3) void rn_main(
    const float* __restrict__ U, const float* __restrict__ V,
    const float* __restrict__ Qb,
    const __bf16* __restrict__ Wrep,
    const float* __restrict__ b2, const float* __restrict__ b3,
    const float* __restrict__ b4,
    float* __restrict__ part) {
  __shared__ __align__(16) __bf16 Hs[HSZ];   // 32 KB
  const int blk = blockIdx.x;
  const int nimg = blk >> 6, iobj = blk & 63;
  const int t = threadIdx.x;
  const int ws = t >> 6, lane = t & 63;
  const int q = lane >> 4, r16 = lane & 15;
  const int rot = (blk >> 3) & 7;

  // phase 0: h1[j][:] = relu(U[n,i,:] + V[n,j,:] + Qb[n,:]) -> Hs
  // V row sweep rotated by iobj so the 64 blocks of an image don't hit the
  // same V lines in lock-step.
  {
    const int c4 = t & 63;
    const int jb = (t >> 6) * 16;
    const f32x4 u4 = *(const f32x4*)&U[(size_t)(nimg * 64 + iobj) * 256 + c4 * 4];
    const f32x4 q4 = *(const f32x4*)&Qb[(size_t)nimg * 256 + c4 * 4];
    const f32x4 uq = u4 + q4;
#pragma unroll
    for (int jj = 0; jj < 16; ++jj) {
      const int row = (jb + jj + iobj) & 63;
      const f32x4 v4 = *(const f32x4*)&V[(size_t)(nimg * 64 + row) * 256 + c4 * 4];
      bf16x4 h;
#pragma unroll
      for (int r = 0; r < 4; ++r) h[r] = (__bf16)fmaxf(uq[r] + v4[r], 0.f);
      *(bf16x4*)(&Hs[hidx(row, c4 * 4)]) = h;
    }
  }
  __syncthreads();

  // lane-resolved weight base inside copy blk&7:
  //  row (output col) = ws*64 + nt*16 + r16, K offset q*8
  const __bf16* wb = Wrep + (size_t)(blk & 7) * WCOPY
                   + (size_t)(ws * 64 + r16) * 256 + q * 8;
  float* part_row = part + (size_t)blk * 256;

  g_layer<false>(Hs, wb,          b2, ws, q, r16, rot, part_row);
  g_layer<false>(Hs, wb +  65536, b3, ws, q, r16, rot, part_row);
  g_layer<true >(Hs, wb + 131072, b4, ws, q, r16, rot, part_row);
}

// ---------------------------------------------------------------------------
// Kernel 3: reduce partials -> context, f-MLP (fp32), log_softmax
// ---------------------------------------------------------------------------
__global__ __launch_bounds__(256) void rn_final(
    const float* __restrict__ part,
    const float* __restrict__ f_w1, const float* __restrict__ f_b1,
    const float* __restrict__ f_w2, const float* __restrict__ f_b2,
    const float* __restrict__ f_w3, const float* __restrict__ f_b3,
    float* __restrict__ out) {
  __shared__ float ctx[256], y1[256], y2[256], sc[2];
  const int n = blockIdx.x, t = threadIdx.x;

  float s = 0.f;
  for (int i = 0; i < 64; ++i) s += part[((size_t)n * 64 + i) * 256 + t];
  ctx[t] = s * (1.0f / 4096.0f);
  __syncthreads();

  float a = f_b1[t];
  for (int k = 0; k < 256; ++k) a += ctx[k] * f_w1[k * 256 + t];
  y1[t] = fmaxf(a, 0.f);
  __syncthreads();

  float b = f_b2[t];
  for (int k = 0; k < 256; ++k) b += y1[k] * f_w2[k * 256 + t];
  y2[t] = fmaxf(b, 0.f);
  __syncthreads();

  if (t < 2) {
    float c = f_b3[t];
    for (int k = 0; k < 256; ++k) c += y2[k] * f_w3[k * 2 + t];
    sc[t] = c;
  }
  __syncthreads();

  if (t == 0) {
    const float s0 = sc[0], s1 = sc[1];
    const float mx = fmaxf(s0, s1);
    const float lse = mx + logf(expf(s0 - mx) + expf(s1 - mx));
    out[n * 2 + 0] = s0 - lse;
    out[n * 2 + 1] = s1 - lse;
  }
}

// ---------------------------------------------------------------------------
extern "C" void kernel_launch(void* const* d_in, const int* in_sizes, int n_in,
                              void* d_out, int out_size, void* d_ws, size_t ws_size,
                              hipStream_t stream) {
  const float* img  = (const float*)d_in[0];
  const float* ques = (const float*)d_in[1];
  const float* g_w1 = (const float*)d_in[2];
  const float* g_b1 = (const float*)d_in[3];
  const float* g_w2 = (const float*)d_in[4];
  const float* g_b2 = (const float*)d_in[5];
  const float* g_w3 = (const float*)d_in[6];
  const float* g_b3 = (const float*)d_in[7];
  const float* g_w4 = (const float*)d_in[8];
  const float* g_b4 = (const float*)d_in[9];
  const float* f_w1 = (const float*)d_in[10];
  const float* f_b1 = (const float*)d_in[11];
  const float* f_w2 = (const float*)d_in[12];
  const float* f_b2 = (const float*)d_in[13];
  const float* f_w3 = (const float*)d_in[14];
  const float* f_b3 = (const float*)d_in[15];
  float* out = (float*)d_out;

  char* ws = (char*)d_ws;
  float*  U    = (float*)(ws);                                 // 4 MB
  float*  V    = (float*)(ws + (size_t)4  * 1048576);          // 4 MB
  float*  part = (float*)(ws + (size_t)8  * 1048576);          // 4 MB
  float*  Qb   = (float*)(ws + (size_t)12 * 1048576);          // 64 KB
  __bf16* Wrep = (__bf16*)(ws + (size_t)12 * 1048576 + 65536); // 8 x 384 KB

  prep_kernel<<<368, 256, 0, stream>>>(img, ques, g_w1, g_b1, g_w2, g_w3, g_w4,
                                       U, V, Qb, Wrep);
  rn_main<<<4096, 256, 0, stream>>>(U, V, Qb, Wrep, g_b2, g_b3, g_b4, part);
  rn_final<<<64, 256, 0, stream>>>(part, f_w1, f_b1, f_w2, f_b2, f_w3, f_b3, out);
}